// Round 15
// baseline (662.588 us; speedup 1.0000x reference)
//
#include <hip/hip_runtime.h>
#include <math.h>

#define NN 128
#define SM 129   // padded LDS stride for 128-wide f32 tiles
#define RS 132   // row-panel stride (doubles)
#define SS 17    // per-wave scratch stride (doubles)
#define SD 130   // padded LDS stride (doubles) for f64 matrix staging

typedef double d4 __attribute__((ext_vector_type(4)));

// ---------------------------------------------------------------------------
// K1 (fused): Laplacian (f32 LDS) + L2 = L @ L via f64 MFMA, one dispatch.
// ---------------------------------------------------------------------------
__global__ __launch_bounds__(512, 1) void k1_lap_pow2(
    const int* __restrict__ src, const int* __restrict__ dst,
    int E, float* __restrict__ Lout, double* __restrict__ L2) {
  extern __shared__ float smf[];            // A/L tile [128*129] + dinv[128]
  float* dinv = smf + NN * SM;
  const int g   = blockIdx.x;
  const int tid = threadIdx.x;
  const int wv = tid >> 6, ln = tid & 63;
  const int m  = ln & 15, kq = ln >> 4;

  int rIdx[4], cIdx[4];
  {
    d4 z = {0.0, 0.0, 0.0, 0.0};
    d4 pr = __builtin_amdgcn_mfma_f64_16x16x4f64((double)m, 1.0, z, 0, 0, 0);
    d4 pc = __builtin_amdgcn_mfma_f64_16x16x4f64(1.0, (double)m, z, 0, 0, 0);
#pragma unroll
    for (int r = 0; r < 4; ++r) {
      rIdx[r] = ((int)(pr[r] * 0.25 + 0.5)) & 15;
      cIdx[r] = ((int)(pc[r] * 0.25 + 0.5)) & 15;
    }
  }

  for (int e = tid; e < NN * NN; e += 512) {
    int i = e >> 7, j = e & 127;
    smf[i * SM + j] = 0.f;
  }
  __syncthreads();
  const int* s = src + (size_t)g * E;
  const int* d = dst + (size_t)g * E;
  for (int e = tid; e < E; e += 512) {
    int a = s[e], b = d[e];
    smf[a * SM + b] = 1.f;   // benign races: all write 1.0
    smf[b * SM + a] = 1.f;
  }
  __syncthreads();
  if (tid < NN) {
    float acc = 0.f;
    for (int j = 0; j < NN; ++j) acc += smf[tid * SM + j];
    dinv[tid] = (acc > 0.f) ? (float)(1.0 / sqrt((double)acc)) : 0.f;
  }
  __syncthreads();
  float* Lg = Lout + (size_t)g * NN * NN;
  for (int e = tid; e < NN * NN; e += 512) {
    int i = e >> 7, j = e & 127;
    float v = ((i == j) ? 1.f : 0.f) - dinv[i] * dinv[j] * smf[i * SM + j];
    Lg[e] = v;
    smf[i * SM + j] = v;     // in-place (each e owned by one thread)
  }
  __syncthreads();

  // L2 = L @ L, wave wv owns row-band 16wv
  d4 acc[8];
#pragma unroll
  for (int cb = 0; cb < 8; ++cb) {
    acc[cb][0] = 0.0; acc[cb][1] = 0.0; acc[cb][2] = 0.0; acc[cb][3] = 0.0;
  }
  for (int kc = 0; kc < 32; ++kc) {
    double a = (double)smf[(16 * wv + m) * SM + 4 * kc + kq];
#pragma unroll
    for (int cb = 0; cb < 8; ++cb) {
      double b = (double)smf[(4 * kc + kq) * SM + 16 * cb + m];
      acc[cb] = __builtin_amdgcn_mfma_f64_16x16x4f64(a, b, acc[cb], 0, 0, 0);
    }
  }
  double* out = L2 + (size_t)g * NN * NN;
#pragma unroll
  for (int cb = 0; cb < 8; ++cb)
#pragma unroll
    for (int r = 0; r < 4; ++r)
      out[(16 * wv + rIdx[r]) * NN + 16 * cb + cIdx[r]] = acc[cb][r];
}

// ---------------------------------------------------------------------------
// K1P34: 128 blocks; job = bid&1 (0: L3 = L2@L, 1: L4 = L2@L2), g = bid>>1.
// ---------------------------------------------------------------------------
__global__ __launch_bounds__(512, 1) void k1_pow34(
    const float* __restrict__ L, const double* __restrict__ L2,
    double* __restrict__ L3, double* __restrict__ L4) {
  extern __shared__ double Bs[];            // 128 x 130 f64
  const int bid = blockIdx.x;
  const int g = bid >> 1, job = bid & 1;
  const int tid = threadIdx.x;
  const int wv = tid >> 6, ln = tid & 63;
  const int m  = ln & 15, kq = ln >> 4;

  int rIdx[4], cIdx[4];
  {
    d4 z = {0.0, 0.0, 0.0, 0.0};
    d4 pr = __builtin_amdgcn_mfma_f64_16x16x4f64((double)m, 1.0, z, 0, 0, 0);
    d4 pc = __builtin_amdgcn_mfma_f64_16x16x4f64(1.0, (double)m, z, 0, 0, 0);
#pragma unroll
    for (int r = 0; r < 4; ++r) {
      rIdx[r] = ((int)(pr[r] * 0.25 + 0.5)) & 15;
      cIdx[r] = ((int)(pc[r] * 0.25 + 0.5)) & 15;
    }
  }

  const float*  Lg  = L  + (size_t)g * NN * NN;
  const double* L2g = L2 + (size_t)g * NN * NN;
  if (job == 0) {
    for (int e = tid; e < NN * NN; e += 512) {
      int i = e >> 7, j = e & 127;
      Bs[i * SD + j] = (double)Lg[e];
    }
  } else {
    for (int e = tid; e < NN * NN; e += 512) {
      int i = e >> 7, j = e & 127;
      Bs[i * SD + j] = L2g[e];
    }
  }
  __syncthreads();

  d4 acc[8];
#pragma unroll
  for (int cb = 0; cb < 8; ++cb) {
    acc[cb][0] = 0.0; acc[cb][1] = 0.0; acc[cb][2] = 0.0; acc[cb][3] = 0.0;
  }
  for (int kc = 0; kc < 32; ++kc) {
    double a = L2g[(16 * wv + m) * NN + 4 * kc + kq];
#pragma unroll
    for (int cb = 0; cb < 8; ++cb) {
      double b = Bs[(4 * kc + kq) * SD + 16 * cb + m];
      acc[cb] = __builtin_amdgcn_mfma_f64_16x16x4f64(a, b, acc[cb], 0, 0, 0);
    }
  }
  double* out = (job == 0 ? L3 : L4) + (size_t)g * NN * NN;
#pragma unroll
  for (int cb = 0; cb < 8; ++cb)
#pragma unroll
    for (int r = 0; r < 4; ++r)
      out[(16 * wv + rIdx[r]) * NN + 16 * cb + cIdx[r]] = acc[cb][r];
}

// ---------------------------------------------------------------------------
// K2 (R14, unchanged): algebraic assembly + blocked GJ with serial-Pi.
// 269us stable; MFMA-busy ~73us (GJ floor), VALU 13%, rest barrier stall.
// ---------------------------------------------------------------------------
__global__ __launch_bounds__(512, 4) void k2_filter(
    const float* __restrict__ L, const double* __restrict__ L2,
    const double* __restrict__ L3, const double* __restrict__ L4,
    const float* __restrict__ C, int NF, float* __restrict__ W) {
  extern __shared__ char smraw[];
  double* Rp  = (double*)smraw;                      // row panel 16x132
  double* Scd = (double*)(smraw + 16 * RS * 8);      // 8 wave scratches 16x17
  double* Pv  = (double*)(smraw + 16 * RS * 8 + 8 * 16 * SS * 8); // Pi 16x17

  const int bid = blockIdx.x;
  const int g = bid / NF, f = bid % NF;
  const int tid = threadIdx.x;
  const int wv = tid >> 6, ln = tid & 63;
  const int m  = ln & 15, kq = ln >> 4;
  double* S = Scd + wv * 16 * SS;

  double csum = 0.0;
  for (int q = 0; q < NF; ++q) { double c = (double)C[q]; csum += c * c; }
  double cn = sqrt(csum); if (cn < 1e-12) cn = 1e-12;
  const double a4 = 6.25e-6;                         // (STEP/2)^4
  const double coef = 1.4142135623730951 * a4 * ((double)C[f] / cn);
  const float  bf = (float)((double)f * 0.1);
  const double bb = (double)bf;
  const double c3 = -4.0 * bb;
  const double c2 = 6.0 * bb * bb;
  const double c1 = -4.0 * bb * bb * bb;
  const double c0 = bb * bb * bb * bb + a4;

  int rIdx[4], cIdx[4];
  {
    d4 z = {0.0, 0.0, 0.0, 0.0};
    d4 pr = __builtin_amdgcn_mfma_f64_16x16x4f64((double)m, 1.0, z, 0, 0, 0);
    d4 pc = __builtin_amdgcn_mfma_f64_16x16x4f64(1.0, (double)m, z, 0, 0, 0);
#pragma unroll
    for (int r = 0; r < 4; ++r) {
      rIdx[r] = ((int)(pr[r] * 0.25 + 0.5)) & 15;
      cIdx[r] = ((int)(pc[r] * 0.25 + 0.5)) & 15;
    }
  }

  // phase A: assemble T (D-layout) from the power matrices -- pure n^2
  const float*  Lg  = L  + (size_t)g * NN * NN;
  const double* L2g = L2 + (size_t)g * NN * NN;
  const double* L3g = L3 + (size_t)g * NN * NN;
  const double* L4g = L4 + (size_t)g * NN * NN;
  d4 T[8];
#pragma unroll
  for (int cb = 0; cb < 8; ++cb)
#pragma unroll
    for (int r = 0; r < 4; ++r) {
      int i = 16 * wv + rIdx[r], j = 16 * cb + cIdx[r];
      int idx = i * NN + j;
      double v = L4g[idx];
      v = fma(c3, L3g[idx], v);
      v = fma(c2, L2g[idx], v);
      v = fma(c1, (double)Lg[idx], v);
      if (i == j) v += c0;
      T[cb][r] = v;
    }

  // phase 4: blocked GJ, 8 steps, 3 block-barriers each, NOT unrolled
#pragma unroll 1
  for (int t = 0; t < 8; ++t) {
    if (wv == t) {
#pragma unroll
      for (int cb = 0; cb < 8; ++cb)
#pragma unroll
        for (int r = 0; r < 4; ++r)
          Rp[rIdx[r] * RS + 16 * cb + cIdx[r]] = T[cb][r];
    }
    __syncthreads();                                 // B1 (Rp visible)

    if (wv == t) {
      double sr[4];
#pragma unroll
      for (int r = 0; r < 4; ++r) sr[r] = Rp[(4 * r + kq) * RS + 16 * t + m];
#pragma unroll
      for (int k = 0; k < 16; ++k) {
        const int kr = k >> 2, kl = k & 3;
        double pv   = __shfl(sr[kr], 16 * kl + k);
        double rowv = __shfl(sr[kr], 16 * kl + m);
        double cv[4];
#pragma unroll
        for (int r = 0; r < 4; ++r) cv[r] = __shfl(sr[r], 16 * kq + k);
        double dp = 1.0 / pv;
#pragma unroll
        for (int r = 0; r < 4; ++r) {
          int i = 4 * r + kq;
          double nv;
          if (i == k)      nv = (m == k) ? dp : rowv * dp;
          else if (m == k) nv = -cv[r] * dp;
          else             nv = fma(-(cv[r] * dp), rowv, sr[r]);
          sr[r] = nv;
        }
      }
#pragma unroll
      for (int r = 0; r < 4; ++r) Pv[(4 * r + kq) * SS + m] = sr[r];
    }
    __syncthreads();                                 // B2 (Pi visible)

#pragma unroll
    for (int cb = 0; cb < 8; ++cb) {
      if (cb != t) continue;
      if (wv == t) {
#pragma unroll
        for (int r = 0; r < 4; ++r) T[cb][r] = Pv[rIdx[r] * SS + cIdx[r]];
      } else {
#pragma unroll
        for (int r = 0; r < 4; ++r) S[rIdx[r] * SS + cIdx[r]] = T[cb][r];
        __builtin_amdgcn_wave_barrier();
        d4 ncv = {0.0, 0.0, 0.0, 0.0};
#pragma unroll
        for (int kc = 0; kc < 4; ++kc) {
          double a = S[m * SS + 4 * kc + kq];
          double b = -Pv[(4 * kc + kq) * SS + m];
          ncv = __builtin_amdgcn_mfma_f64_16x16x4f64(a, b, ncv, 0, 0, 0);
        }
        T[cb] = ncv;
        __builtin_amdgcn_wave_barrier();
#pragma unroll
        for (int r = 0; r < 4; ++r) S[rIdx[r] * SS + cIdx[r]] = T[cb][r];
      }
    }
    __builtin_amdgcn_wave_barrier();

    const double* asrc = (wv == t) ? Pv : S;
#pragma unroll
    for (int cb = 0; cb < 8; ++cb) {
      if (cb == t) continue;
      d4 acc;
      if (wv == t) { acc[0] = 0.0; acc[1] = 0.0; acc[2] = 0.0; acc[3] = 0.0; }
      else         { acc = T[cb]; }
#pragma unroll
      for (int kc = 0; kc < 4; ++kc) {
        double a = asrc[m * SS + 4 * kc + kq];
        double b = Rp[(4 * kc + kq) * RS + 16 * cb + m];
        acc = __builtin_amdgcn_mfma_f64_16x16x4f64(a, b, acc, 0, 0, 0);
      }
      T[cb] = acc;
    }
    __syncthreads();                                 // B3 (Rp/Pv reads done)
  }

  // phase 5: W += coef * K^{-1}
  float* Wg = W + (size_t)g * NN * NN;
#pragma unroll
  for (int cb = 0; cb < 8; ++cb)
#pragma unroll
    for (int r = 0; r < 4; ++r)
      atomicAdd(&Wg[(16 * wv + rIdx[r]) * NN + 16 * cb + cIdx[r]],
                (float)(coef * T[cb][r]));
}

// ---------------------------------------------------------------------------
// K3 (R15): fully MFMA-ized fused kernel. Key point: with MFMA, the Gram
// G[i][j] = sum_d Y[i][d]Y[j][d] needs NO transposed tile -- both A-fragment
// (Y[16w+m][4kc+kq]) and B-fragment (Y[16cb+m][4kc+kq]) are row-major reads
// of the same Y tile (the k-dim is d). Phases:
//   1. load W, X-chunk (f32 LDS)
//   2. Y = X - W@X via f64 MFMA (operands cvt from f32 LDS; k2-R9 pattern)
//   3. scatter Y D-layout -> row-major into the dead W region
//   4. Gram via f64 MFMA from that tile -> atomics into G; emb col-sums
// R13 version: two fp32 VALU matmuls + transpose, LDS-read-bound (~145us).
// ---------------------------------------------------------------------------
__global__ __launch_bounds__(512, 1) void k3_fused(
    const float* __restrict__ x, const float* __restrict__ rs,
    const float* __restrict__ W, float* __restrict__ G,
    float* __restrict__ emb, int F0, int R, int DTOT, int NCH,
    float rscale) {
  extern __shared__ float sm3[];
  float* ldsW = sm3;                 // W tile, later Y (row-major)
  float* ldsX = sm3 + NN * SM;       // X chunk
  const int bid = blockIdx.x;
  const int g = bid / NCH;
  const int c = bid % NCH;
  const int d0 = c * 128;
  const int tid = threadIdx.x;
  const int wv = tid >> 6, ln = tid & 63;
  const int m  = ln & 15, kq = ln >> 4;

  int rIdx[4], cIdx[4];
  {
    d4 z = {0.0, 0.0, 0.0, 0.0};
    d4 pr = __builtin_amdgcn_mfma_f64_16x16x4f64((double)m, 1.0, z, 0, 0, 0);
    d4 pc = __builtin_amdgcn_mfma_f64_16x16x4f64(1.0, (double)m, z, 0, 0, 0);
#pragma unroll
    for (int r = 0; r < 4; ++r) {
      rIdx[r] = ((int)(pr[r] * 0.25 + 0.5)) & 15;
      cIdx[r] = ((int)(pc[r] * 0.25 + 0.5)) & 15;
    }
  }

  const float* Wg = W + (size_t)g * NN * NN;
  for (int e = tid; e < NN * NN; e += 512) {
    int i = e >> 7, j = e & 127;
    ldsW[i * SM + j] = Wg[e];
  }
  const float* xg = x + (size_t)g * NN * F0;
  const float* rg = rs + (size_t)g * NN * R;
  for (int e = tid; e < NN * NN; e += 512) {
    int i = e >> 7, dl = e & 127;
    int d = d0 + dl;
    float v = 0.f;
    if (d < DTOT) v = (d < F0) ? xg[i * F0 + d] : rg[i * R + (d - F0)] * rscale;
    ldsX[i * SM + dl] = v;
  }
  __syncthreads();

  // phase 2: T = W @ Xc  (wave wv owns row-band 16wv), then T := X - T
  d4 T[8];
#pragma unroll
  for (int cb = 0; cb < 8; ++cb) {
    T[cb][0] = 0.0; T[cb][1] = 0.0; T[cb][2] = 0.0; T[cb][3] = 0.0;
  }
  for (int kc = 0; kc < 32; ++kc) {
    double a = (double)ldsW[(16 * wv + m) * SM + 4 * kc + kq];
#pragma unroll
    for (int cb = 0; cb < 8; ++cb) {
      double b = (double)ldsX[(4 * kc + kq) * SM + 16 * cb + m];
      T[cb] = __builtin_amdgcn_mfma_f64_16x16x4f64(a, b, T[cb], 0, 0, 0);
    }
  }
#pragma unroll
  for (int cb = 0; cb < 8; ++cb)
#pragma unroll
    for (int r = 0; r < 4; ++r)
      T[cb][r] = (double)ldsX[(16 * wv + rIdx[r]) * SM + 16 * cb + cIdx[r]]
                 - T[cb][r];
  __syncthreads();   // all W-tile reads done -> overwrite with Y (row-major)

  // phase 3: Y into ldsW region (D-layout scatter -> row-major target)
#pragma unroll
  for (int cb = 0; cb < 8; ++cb)
#pragma unroll
    for (int r = 0; r < 4; ++r)
      ldsW[(16 * wv + rIdx[r]) * SM + 16 * cb + cIdx[r]] = (float)T[cb][r];
  __syncthreads();

  // phase 4: Gram via MFMA (A and B both row-major reads of Y)
  d4 Ga[8];
#pragma unroll
  for (int cb = 0; cb < 8; ++cb) {
    Ga[cb][0] = 0.0; Ga[cb][1] = 0.0; Ga[cb][2] = 0.0; Ga[cb][3] = 0.0;
  }
  for (int kc = 0; kc < 32; ++kc) {
    double a = (double)ldsW[(16 * wv + m) * SM + 4 * kc + kq];
#pragma unroll
    for (int cb = 0; cb < 8; ++cb) {
      double b = (double)ldsW[(16 * cb + m) * SM + 4 * kc + kq];
      Ga[cb] = __builtin_amdgcn_mfma_f64_16x16x4f64(a, b, Ga[cb], 0, 0, 0);
    }
  }
  float* Gg = G + (size_t)g * NN * NN;
#pragma unroll
  for (int cb = 0; cb < 8; ++cb)
#pragma unroll
    for (int r = 0; r < 4; ++r)
      atomicAdd(&Gg[(16 * wv + rIdx[r]) * NN + 16 * cb + cIdx[r]],
                (float)Ga[cb][r]);

  // emb column sums of Y (row-major tile; consecutive-thread reads)
  if (tid < 128) {
    int d = d0 + tid;
    if (d < DTOT) {
      float s = 0.f;
      for (int i = 0; i < NN; ++i) s += ldsW[i * SM + tid];
      emb[(size_t)g * 1152 + d] = s * (1.f / 128.f);
    }
  }
}

// ---------------------------------------------------------------------------
// K45 (fused): blocks 0..63 = k4 (sp terms from G); 64..127 = k5a (cdist)
// ---------------------------------------------------------------------------
__global__ __launch_bounds__(256) void k45_fused(
    const float* __restrict__ G, double* __restrict__ spt,
    const float* __restrict__ emb, float* __restrict__ Dm, int DTOT) {
  __shared__ float inr[NN];
  __shared__ double red[4];
  const int bid = blockIdx.x, tid = threadIdx.x;
  if (bid < 64) {
    const int g = bid;
    const float* Gg = G + (size_t)g * NN * NN;
    if (tid < NN) {
      float n = sqrtf(fmaxf(Gg[tid * NN + tid], 0.f));
      inr[tid] = 1.f / fmaxf(n, 1e-12f);
    }
    __syncthreads();
    double s = 0.0;
    for (int e = tid; e < NN * NN; e += 256) {
      int i = e >> 7, j = e & 127;
      s += (double)(fabsf(Gg[e]) * inr[i] * inr[j]);
    }
    for (int off = 32; off; off >>= 1) s += __shfl_down(s, off);
    int wave = tid >> 6, lane = tid & 63;
    if (lane == 0) red[wave] = s;
    __syncthreads();
    if (tid == 0) spt[g] = -(red[0] + red[1] + red[2] + red[3]) / (double)(NN * NN);
  } else {
    const int i = bid - 64;
    const int wv = tid >> 6, l = tid & 63;
    float ei[18];
#pragma unroll
    for (int s = 0; s < 18; ++s) {
      int d = l + 64 * s;
      ei[s] = (d < DTOT) ? emb[(size_t)i * 1152 + d] : 0.f;
    }
    for (int jj = 0; jj < 16; ++jj) {
      int j = 4 * jj + wv;
      float acc = 0.f;
#pragma unroll
      for (int s = 0; s < 18; ++s) {
        int d = l + 64 * s;
        if (d < DTOT) {
          float df = ei[s] - emb[(size_t)j * 1152 + d];
          acc = fmaf(df, df, acc);
        }
      }
      for (int off = 32; off; off >>= 1) acc += __shfl_down(acc, off);
      if (l == 0) Dm[i * 64 + j] = (acc > 0.f) ? sqrtf(acc) : 0.f;
    }
  }
}

// ---------------------------------------------------------------------------
// K5b: final scalar (single wave)
// ---------------------------------------------------------------------------
__global__ __launch_bounds__(64) void k5b_final(
    const float* __restrict__ Dm, const double* __restrict__ spt,
    const float* __restrict__ C, int NF,
    const int* __restrict__ ncls, float* __restrict__ out) {
  const int lane = threadIdx.x;
  const int nc = ncls[0];
  double spf = spt[lane] * exp(-((double)(64 - lane)) * log(64.0));
  for (int off = 32; off; off >>= 1) spf += __shfl_down(spf, off);

  double hl1 = 0.0, hl2 = 0.0;
  const double beta = 1.0 / (double)nc + 1e-13;
  for (int cc = 0; cc < nc; ++cc) {
    bool ip = (lane % nc) == cc;
    double ps = 0.0, ns = 0.0;
    for (int j = 0; j < 64; ++j) {
      double dv = (double)Dm[lane * 64 + j];
      bool jp = (j % nc) == cc;
      if (ip && jp) ps += dv;
      if (!ip && !jp) ns += dv;
    }
    for (int off = 32; off; off >>= 1) {
      ps += __shfl_down(ps, off);
      ns += __shfl_down(ns, off);
    }
    int npos = 0;
    for (int q = 0; q < 64; ++q) if (q % nc == cc) npos++;
    int nneg = 64 - npos;
    hl2 += ps / ((double)npos * (double)npos);
    hl1 += -(ns / ((double)nneg * (double)nneg)) / beta;
  }
  if (lane == 0) {
    double l1 = 0.0, l2 = 0.0;
    for (int q = 0; q < NF; ++q) { double cv = (double)C[q]; l1 += fabs(cv); l2 += cv * cv; }
    l2 = sqrt(l2); if (l2 < 1e-12) l2 = 1e-12;
    double dims = sqrt((double)NF);
    double sc = (dims - l1 / l2) / (dims - 1.0);
    out[0] = (float)(sc + hl2 + hl1 + spf);
  }
}

// ---------------------------------------------------------------------------
extern "C" void kernel_launch(void* const* d_in, const int* in_sizes, int n_in,
                              void* d_out, int out_size, void* d_ws, size_t ws_size,
                              hipStream_t stream) {
  (void)n_in; (void)out_size; (void)ws_size;
  const float* x    = (const float*)d_in[0];
  const float* rs   = (const float*)d_in[1];
  const float* C    = (const float*)d_in[2];
  const int*   esrc = (const int*)d_in[3];
  const int*   edst = (const int*)d_in[4];
  const int*   ncls = (const int*)d_in[5];
  float* out = (float*)d_out;

  const int F0   = in_sizes[0] / (64 * 128);
  const int R    = in_sizes[1] / (64 * 128);
  const int NF   = in_sizes[2];
  const int E    = in_sizes[3] / 64;
  const int DTOT = F0 + R;
  const int NCH  = (DTOT + 127) / 128;
  const float rscale = (float)(1.0 / sqrt((double)R));

  char* ws = (char*)d_ws;
  size_t off = 0;
  float*  L    = (float*)(ws + off);  off += (size_t)64 * NN * NN * 4;
  float*  W    = (float*)(ws + off);  off += (size_t)64 * NN * NN * 4;
  float*  G    = (float*)(ws + off);  off += (size_t)64 * NN * NN * 4;
  double* L2d  = (double*)(ws + off); off += (size_t)64 * NN * NN * 8;
  double* L3d  = (double*)(ws + off); off += (size_t)64 * NN * NN * 8;
  double* L4d  = (double*)(ws + off); off += (size_t)64 * NN * NN * 8;
  float*  emb  = (float*)(ws + off);  off += (size_t)64 * 1152 * 4;
  double* spt  = (double*)(ws + off); off += (size_t)64 * 8;
  float*  Dm   = (float*)(ws + off);  off += (size_t)64 * 64 * 4;

  hipMemsetAsync(W, 0, (size_t)64 * NN * NN * 4, stream);
  hipMemsetAsync(G, 0, (size_t)64 * NN * NN * 4, stream);

  const int lds1 = (NN * SM + NN) * 4;             // 66560
  const int ldsp = NN * SD * 8;                    // 133120 (f64 staging)
  const int lds2 = 16 * RS * 8 + 8 * 16 * SS * 8 + 16 * SS * 8;  // 36480
  const int lds3 = (NN * SM) * 4 * 2;              // 132096
  hipFuncSetAttribute((const void*)k1_lap_pow2, hipFuncAttributeMaxDynamicSharedMemorySize, lds1);
  hipFuncSetAttribute((const void*)k1_pow34,    hipFuncAttributeMaxDynamicSharedMemorySize, ldsp);
  hipFuncSetAttribute((const void*)k2_filter,   hipFuncAttributeMaxDynamicSharedMemorySize, lds2);
  hipFuncSetAttribute((const void*)k3_fused,    hipFuncAttributeMaxDynamicSharedMemorySize, lds3);

  k1_lap_pow2<<<64, 512, lds1, stream>>>(esrc, edst, E, L, L2d);
  k1_pow34<<<128, 512, ldsp, stream>>>(L, L2d, L3d, L4d);
  k2_filter<<<64 * NF, 512, lds2, stream>>>(L, L2d, L3d, L4d, C, NF, W);
  k3_fused<<<64 * NCH, 512, lds3, stream>>>(x, rs, W, G, emb, F0, R, DTOT, NCH, rscale);
  k45_fused<<<128, 256, 0, stream>>>(G, spt, emb, Dm, DTOT);
  k5b_final<<<1, 64, 0, stream>>>(Dm, spt, C, NF, ncls, out);
}

// Round 16
// 641.183 us; speedup vs baseline: 1.0334x; 1.0334x over previous
//
#include <hip/hip_runtime.h>
#include <math.h>

#define NN 128
#define SM 129   // padded LDS stride for 128-wide f32 tiles
#define TS 132   // k3 tile stride (16B-aligned rows -> float4 LDS loads)
#define RS 132   // row-panel stride (doubles)
#define SS 17    // per-wave scratch stride (doubles)
#define SD 130   // padded LDS stride (doubles) for f64 matrix staging
#define EP 132   // emb-partial stride (floats)

typedef double d4 __attribute__((ext_vector_type(4)));

// ---------------------------------------------------------------------------
// K1 (fused): Laplacian (f32 LDS) + L2 = L @ L via f64 MFMA, one dispatch.
// ---------------------------------------------------------------------------
__global__ __launch_bounds__(512, 1) void k1_lap_pow2(
    const int* __restrict__ src, const int* __restrict__ dst,
    int E, float* __restrict__ Lout, double* __restrict__ L2) {
  extern __shared__ float smf[];            // A/L tile [128*129] + dinv[128]
  float* dinv = smf + NN * SM;
  const int g   = blockIdx.x;
  const int tid = threadIdx.x;
  const int wv = tid >> 6, ln = tid & 63;
  const int m  = ln & 15, kq = ln >> 4;

  int rIdx[4], cIdx[4];
  {
    d4 z = {0.0, 0.0, 0.0, 0.0};
    d4 pr = __builtin_amdgcn_mfma_f64_16x16x4f64((double)m, 1.0, z, 0, 0, 0);
    d4 pc = __builtin_amdgcn_mfma_f64_16x16x4f64(1.0, (double)m, z, 0, 0, 0);
#pragma unroll
    for (int r = 0; r < 4; ++r) {
      rIdx[r] = ((int)(pr[r] * 0.25 + 0.5)) & 15;
      cIdx[r] = ((int)(pc[r] * 0.25 + 0.5)) & 15;
    }
  }

  for (int e = tid; e < NN * NN; e += 512) {
    int i = e >> 7, j = e & 127;
    smf[i * SM + j] = 0.f;
  }
  __syncthreads();
  const int* s = src + (size_t)g * E;
  const int* d = dst + (size_t)g * E;
  for (int e = tid; e < E; e += 512) {
    int a = s[e], b = d[e];
    smf[a * SM + b] = 1.f;   // benign races: all write 1.0
    smf[b * SM + a] = 1.f;
  }
  __syncthreads();
  if (tid < NN) {
    float acc = 0.f;
    for (int j = 0; j < NN; ++j) acc += smf[tid * SM + j];
    dinv[tid] = (acc > 0.f) ? (float)(1.0 / sqrt((double)acc)) : 0.f;
  }
  __syncthreads();
  float* Lg = Lout + (size_t)g * NN * NN;
  for (int e = tid; e < NN * NN; e += 512) {
    int i = e >> 7, j = e & 127;
    float v = ((i == j) ? 1.f : 0.f) - dinv[i] * dinv[j] * smf[i * SM + j];
    Lg[e] = v;
    smf[i * SM + j] = v;     // in-place (each e owned by one thread)
  }
  __syncthreads();

  // L2 = L @ L, wave wv owns row-band 16wv
  d4 acc[8];
#pragma unroll
  for (int cb = 0; cb < 8; ++cb) {
    acc[cb][0] = 0.0; acc[cb][1] = 0.0; acc[cb][2] = 0.0; acc[cb][3] = 0.0;
  }
  for (int kc = 0; kc < 32; ++kc) {
    double a = (double)smf[(16 * wv + m) * SM + 4 * kc + kq];
#pragma unroll
    for (int cb = 0; cb < 8; ++cb) {
      double b = (double)smf[(4 * kc + kq) * SM + 16 * cb + m];
      acc[cb] = __builtin_amdgcn_mfma_f64_16x16x4f64(a, b, acc[cb], 0, 0, 0);
    }
  }
  double* out = L2 + (size_t)g * NN * NN;
#pragma unroll
  for (int cb = 0; cb < 8; ++cb)
#pragma unroll
    for (int r = 0; r < 4; ++r)
      out[(16 * wv + rIdx[r]) * NN + 16 * cb + cIdx[r]] = acc[cb][r];
}

// ---------------------------------------------------------------------------
// K1P34: 128 blocks; job = bid&1 (0: L3 = L2@L, 1: L4 = L2@L2), g = bid>>1.
// ---------------------------------------------------------------------------
__global__ __launch_bounds__(512, 1) void k1_pow34(
    const float* __restrict__ L, const double* __restrict__ L2,
    double* __restrict__ L3, double* __restrict__ L4) {
  extern __shared__ double Bs[];            // 128 x 130 f64
  const int bid = blockIdx.x;
  const int g = bid >> 1, job = bid & 1;
  const int tid = threadIdx.x;
  const int wv = tid >> 6, ln = tid & 63;
  const int m  = ln & 15, kq = ln >> 4;

  int rIdx[4], cIdx[4];
  {
    d4 z = {0.0, 0.0, 0.0, 0.0};
    d4 pr = __builtin_amdgcn_mfma_f64_16x16x4f64((double)m, 1.0, z, 0, 0, 0);
    d4 pc = __builtin_amdgcn_mfma_f64_16x16x4f64(1.0, (double)m, z, 0, 0, 0);
#pragma unroll
    for (int r = 0; r < 4; ++r) {
      rIdx[r] = ((int)(pr[r] * 0.25 + 0.5)) & 15;
      cIdx[r] = ((int)(pc[r] * 0.25 + 0.5)) & 15;
    }
  }

  const float*  Lg  = L  + (size_t)g * NN * NN;
  const double* L2g = L2 + (size_t)g * NN * NN;
  if (job == 0) {
    for (int e = tid; e < NN * NN; e += 512) {
      int i = e >> 7, j = e & 127;
      Bs[i * SD + j] = (double)Lg[e];
    }
  } else {
    for (int e = tid; e < NN * NN; e += 512) {
      int i = e >> 7, j = e & 127;
      Bs[i * SD + j] = L2g[e];
    }
  }
  __syncthreads();

  d4 acc[8];
#pragma unroll
  for (int cb = 0; cb < 8; ++cb) {
    acc[cb][0] = 0.0; acc[cb][1] = 0.0; acc[cb][2] = 0.0; acc[cb][3] = 0.0;
  }
  for (int kc = 0; kc < 32; ++kc) {
    double a = L2g[(16 * wv + m) * NN + 4 * kc + kq];
#pragma unroll
    for (int cb = 0; cb < 8; ++cb) {
      double b = Bs[(4 * kc + kq) * SD + 16 * cb + m];
      acc[cb] = __builtin_amdgcn_mfma_f64_16x16x4f64(a, b, acc[cb], 0, 0, 0);
    }
  }
  double* out = (job == 0 ? L3 : L4) + (size_t)g * NN * NN;
#pragma unroll
  for (int cb = 0; cb < 8; ++cb)
#pragma unroll
    for (int r = 0; r < 4; ++r)
      out[(16 * wv + rIdx[r]) * NN + 16 * cb + cIdx[r]] = acc[cb][r];
}

// ---------------------------------------------------------------------------
// K2 (R14, unchanged): algebraic assembly + blocked GJ with serial-Pi.
// 269us stable; MFMA-busy ~73us (GJ floor), VALU 13%, rest barrier stall.
// ---------------------------------------------------------------------------
__global__ __launch_bounds__(512, 4) void k2_filter(
    const float* __restrict__ L, const double* __restrict__ L2,
    const double* __restrict__ L3, const double* __restrict__ L4,
    const float* __restrict__ C, int NF, float* __restrict__ W) {
  extern __shared__ char smraw[];
  double* Rp  = (double*)smraw;                      // row panel 16x132
  double* Scd = (double*)(smraw + 16 * RS * 8);      // 8 wave scratches 16x17
  double* Pv  = (double*)(smraw + 16 * RS * 8 + 8 * 16 * SS * 8); // Pi 16x17

  const int bid = blockIdx.x;
  const int g = bid / NF, f = bid % NF;
  const int tid = threadIdx.x;
  const int wv = tid >> 6, ln = tid & 63;
  const int m  = ln & 15, kq = ln >> 4;
  double* S = Scd + wv * 16 * SS;

  double csum = 0.0;
  for (int q = 0; q < NF; ++q) { double c = (double)C[q]; csum += c * c; }
  double cn = sqrt(csum); if (cn < 1e-12) cn = 1e-12;
  const double a4 = 6.25e-6;                         // (STEP/2)^4
  const double coef = 1.4142135623730951 * a4 * ((double)C[f] / cn);
  const float  bf = (float)((double)f * 0.1);
  const double bb = (double)bf;
  const double c3 = -4.0 * bb;
  const double c2 = 6.0 * bb * bb;
  const double c1 = -4.0 * bb * bb * bb;
  const double c0 = bb * bb * bb * bb + a4;

  int rIdx[4], cIdx[4];
  {
    d4 z = {0.0, 0.0, 0.0, 0.0};
    d4 pr = __builtin_amdgcn_mfma_f64_16x16x4f64((double)m, 1.0, z, 0, 0, 0);
    d4 pc = __builtin_amdgcn_mfma_f64_16x16x4f64(1.0, (double)m, z, 0, 0, 0);
#pragma unroll
    for (int r = 0; r < 4; ++r) {
      rIdx[r] = ((int)(pr[r] * 0.25 + 0.5)) & 15;
      cIdx[r] = ((int)(pc[r] * 0.25 + 0.5)) & 15;
    }
  }

  // phase A: assemble T (D-layout) from the power matrices -- pure n^2
  const float*  Lg  = L  + (size_t)g * NN * NN;
  const double* L2g = L2 + (size_t)g * NN * NN;
  const double* L3g = L3 + (size_t)g * NN * NN;
  const double* L4g = L4 + (size_t)g * NN * NN;
  d4 T[8];
#pragma unroll
  for (int cb = 0; cb < 8; ++cb)
#pragma unroll
    for (int r = 0; r < 4; ++r) {
      int i = 16 * wv + rIdx[r], j = 16 * cb + cIdx[r];
      int idx = i * NN + j;
      double v = L4g[idx];
      v = fma(c3, L3g[idx], v);
      v = fma(c2, L2g[idx], v);
      v = fma(c1, (double)Lg[idx], v);
      if (i == j) v += c0;
      T[cb][r] = v;
    }

  // phase 4: blocked GJ, 8 steps, 3 block-barriers each, NOT unrolled
#pragma unroll 1
  for (int t = 0; t < 8; ++t) {
    if (wv == t) {
#pragma unroll
      for (int cb = 0; cb < 8; ++cb)
#pragma unroll
        for (int r = 0; r < 4; ++r)
          Rp[rIdx[r] * RS + 16 * cb + cIdx[r]] = T[cb][r];
    }
    __syncthreads();                                 // B1 (Rp visible)

    if (wv == t) {
      double sr[4];
#pragma unroll
      for (int r = 0; r < 4; ++r) sr[r] = Rp[(4 * r + kq) * RS + 16 * t + m];
#pragma unroll
      for (int k = 0; k < 16; ++k) {
        const int kr = k >> 2, kl = k & 3;
        double pv   = __shfl(sr[kr], 16 * kl + k);
        double rowv = __shfl(sr[kr], 16 * kl + m);
        double cv[4];
#pragma unroll
        for (int r = 0; r < 4; ++r) cv[r] = __shfl(sr[r], 16 * kq + k);
        double dp = 1.0 / pv;
#pragma unroll
        for (int r = 0; r < 4; ++r) {
          int i = 4 * r + kq;
          double nv;
          if (i == k)      nv = (m == k) ? dp : rowv * dp;
          else if (m == k) nv = -cv[r] * dp;
          else             nv = fma(-(cv[r] * dp), rowv, sr[r]);
          sr[r] = nv;
        }
      }
#pragma unroll
      for (int r = 0; r < 4; ++r) Pv[(4 * r + kq) * SS + m] = sr[r];
    }
    __syncthreads();                                 // B2 (Pi visible)

#pragma unroll
    for (int cb = 0; cb < 8; ++cb) {
      if (cb != t) continue;
      if (wv == t) {
#pragma unroll
        for (int r = 0; r < 4; ++r) T[cb][r] = Pv[rIdx[r] * SS + cIdx[r]];
      } else {
#pragma unroll
        for (int r = 0; r < 4; ++r) S[rIdx[r] * SS + cIdx[r]] = T[cb][r];
        __builtin_amdgcn_wave_barrier();
        d4 ncv = {0.0, 0.0, 0.0, 0.0};
#pragma unroll
        for (int kc = 0; kc < 4; ++kc) {
          double a = S[m * SS + 4 * kc + kq];
          double b = -Pv[(4 * kc + kq) * SS + m];
          ncv = __builtin_amdgcn_mfma_f64_16x16x4f64(a, b, ncv, 0, 0, 0);
        }
        T[cb] = ncv;
        __builtin_amdgcn_wave_barrier();
#pragma unroll
        for (int r = 0; r < 4; ++r) S[rIdx[r] * SS + cIdx[r]] = T[cb][r];
      }
    }
    __builtin_amdgcn_wave_barrier();

    const double* asrc = (wv == t) ? Pv : S;
#pragma unroll
    for (int cb = 0; cb < 8; ++cb) {
      if (cb == t) continue;
      d4 acc;
      if (wv == t) { acc[0] = 0.0; acc[1] = 0.0; acc[2] = 0.0; acc[3] = 0.0; }
      else         { acc = T[cb]; }
#pragma unroll
      for (int kc = 0; kc < 4; ++kc) {
        double a = asrc[m * SS + 4 * kc + kq];
        double b = Rp[(4 * kc + kq) * RS + 16 * cb + m];
        acc = __builtin_amdgcn_mfma_f64_16x16x4f64(a, b, acc, 0, 0, 0);
      }
      T[cb] = acc;
    }
    __syncthreads();                                 // B3 (Rp/Pv reads done)
  }

  // phase 5: W += coef * K^{-1}
  float* Wg = W + (size_t)g * NN * NN;
#pragma unroll
  for (int cb = 0; cb < 8; ++cb)
#pragma unroll
    for (int r = 0; r < 4; ++r)
      atomicAdd(&Wg[(16 * wv + rIdx[r]) * NN + 16 * cb + cIdx[r]],
                (float)(coef * T[cb][r]));
}

// ---------------------------------------------------------------------------
// K3 (R16): R13's proven fp32 VALU structure (646us config), with tile
// stride 132 so the 4-consecutive a-operand LDS reads become one
// ds_read_b128 (rows 16B-aligned; 16-lane broadcast, conflict-free).
// R15 lesson: f64-MFMA version didn't cut LDS issue -> reverted.
// ---------------------------------------------------------------------------
__global__ __launch_bounds__(512, 1) void k3_fused(
    const float* __restrict__ x, const float* __restrict__ rs,
    const float* __restrict__ W, float* __restrict__ G,
    float* __restrict__ emb, int F0, int R, int DTOT, int NCH,
    float rscale) {
  extern __shared__ float sm3[];
  float* ldsW = sm3;                 // 128*132, later yT
  float* ldsX = sm3 + NN * TS;       // 128*132, later emb partials (32x132)
  const int bid = blockIdx.x;
  const int g = bid / NCH;
  const int c = bid % NCH;
  const int d0 = c * 128;
  const int tid = threadIdx.x, tr = tid >> 4, tc = tid & 15;

  const float* Wg = W + (size_t)g * NN * NN;
  for (int e = tid; e < NN * NN; e += 512) {
    int k = e >> 7, i = e & 127;
    ldsW[k * TS + i] = Wg[e];
  }
  const float* xg = x + (size_t)g * NN * F0;
  const float* rg = rs + (size_t)g * NN * R;
  for (int e = tid; e < NN * NN; e += 512) {
    int k = e >> 7, dl = e & 127;
    int d = d0 + dl;
    float v = 0.f;
    if (d < DTOT) v = (d < F0) ? xg[k * F0 + d] : rg[k * R + (d - F0)] * rscale;
    ldsX[k * TS + dl] = v;
  }
  __syncthreads();

  float acc[4][8];
#pragma unroll
  for (int v = 0; v < 4; ++v)
#pragma unroll
    for (int u = 0; u < 8; ++u) acc[v][u] = 0.f;
  for (int k = 0; k < NN; ++k) {
    float4 w4 = *(const float4*)(ldsW + k * TS + 4 * tr);   // W symmetric rows
    float xv[8];
#pragma unroll
    for (int u = 0; u < 8; ++u) xv[u] = ldsX[k * TS + tc + 16 * u];
    float wvv[4] = {w4.x, w4.y, w4.z, w4.w};
#pragma unroll
    for (int v = 0; v < 4; ++v)
#pragma unroll
      for (int u = 0; u < 8; ++u) acc[v][u] = fmaf(wvv[v], xv[u], acc[v][u]);
  }
#pragma unroll
  for (int v = 0; v < 4; ++v)
#pragma unroll
    for (int u = 0; u < 8; ++u)
      acc[v][u] = ldsX[(4 * tr + v) * TS + tc + 16 * u] - acc[v][u];
  __syncthreads();

#pragma unroll
  for (int v = 0; v < 4; ++v)
#pragma unroll
    for (int u = 0; u < 8; ++u)
      ldsW[(tc + 16 * u) * TS + 4 * tr + v] = acc[v][u];
#pragma unroll
  for (int u = 0; u < 8; ++u) {
    float s = 0.f;
#pragma unroll
    for (int v = 0; v < 4; ++v) s += acc[v][u];
    ldsX[tr * EP + tc + 16 * u] = s;
  }
  __syncthreads();

  float gg[4][8];
#pragma unroll
  for (int v = 0; v < 4; ++v)
#pragma unroll
    for (int u = 0; u < 8; ++u) gg[v][u] = 0.f;
  for (int dl = 0; dl < NN; ++dl) {
    float4 a4v = *(const float4*)(ldsW + dl * TS + 4 * tr);
    float bv[8];
#pragma unroll
    for (int u = 0; u < 8; ++u) bv[u] = ldsW[dl * TS + tc + 16 * u];
    float av[4] = {a4v.x, a4v.y, a4v.z, a4v.w};
#pragma unroll
    for (int v = 0; v < 4; ++v)
#pragma unroll
      for (int u = 0; u < 8; ++u) gg[v][u] = fmaf(av[v], bv[u], gg[v][u]);
  }
  float* Gg = G + (size_t)g * NN * NN;
#pragma unroll
  for (int v = 0; v < 4; ++v)
#pragma unroll
    for (int u = 0; u < 8; ++u)
      atomicAdd(&Gg[(4 * tr + v) * NN + tc + 16 * u], gg[v][u]);

  if (tid < 128) {
    int d = d0 + tid;
    if (d < DTOT) {
      float s = 0.f;
      for (int tt = 0; tt < 32; ++tt) s += ldsX[tt * EP + tid];
      emb[(size_t)g * 1152 + d] = s * (1.f / 128.f);
    }
  }
}

// ---------------------------------------------------------------------------
// K45 (fused): blocks 0..63 = k4 (sp terms from G); 64..127 = k5a (cdist)
// ---------------------------------------------------------------------------
__global__ __launch_bounds__(256) void k45_fused(
    const float* __restrict__ G, double* __restrict__ spt,
    const float* __restrict__ emb, float* __restrict__ Dm, int DTOT) {
  __shared__ float inr[NN];
  __shared__ double red[4];
  const int bid = blockIdx.x, tid = threadIdx.x;
  if (bid < 64) {
    const int g = bid;
    const float* Gg = G + (size_t)g * NN * NN;
    if (tid < NN) {
      float n = sqrtf(fmaxf(Gg[tid * NN + tid], 0.f));
      inr[tid] = 1.f / fmaxf(n, 1e-12f);
    }
    __syncthreads();
    double s = 0.0;
    for (int e = tid; e < NN * NN; e += 256) {
      int i = e >> 7, j = e & 127;
      s += (double)(fabsf(Gg[e]) * inr[i] * inr[j]);
    }
    for (int off = 32; off; off >>= 1) s += __shfl_down(s, off);
    int wave = tid >> 6, lane = tid & 63;
    if (lane == 0) red[wave] = s;
    __syncthreads();
    if (tid == 0) spt[g] = -(red[0] + red[1] + red[2] + red[3]) / (double)(NN * NN);
  } else {
    const int i = bid - 64;
    const int wv = tid >> 6, l = tid & 63;
    float ei[18];
#pragma unroll
    for (int s = 0; s < 18; ++s) {
      int d = l + 64 * s;
      ei[s] = (d < DTOT) ? emb[(size_t)i * 1152 + d] : 0.f;
    }
    for (int jj = 0; jj < 16; ++jj) {
      int j = 4 * jj + wv;
      float acc = 0.f;
#pragma unroll
      for (int s = 0; s < 18; ++s) {
        int d = l + 64 * s;
        if (d < DTOT) {
          float df = ei[s] - emb[(size_t)j * 1152 + d];
          acc = fmaf(df, df, acc);
        }
      }
      for (int off = 32; off; off >>= 1) acc += __shfl_down(acc, off);
      if (l == 0) Dm[i * 64 + j] = (acc > 0.f) ? sqrtf(acc) : 0.f;
    }
  }
}

// ---------------------------------------------------------------------------
// K5b: final scalar (single wave)
// ---------------------------------------------------------------------------
__global__ __launch_bounds__(64) void k5b_final(
    const float* __restrict__ Dm, const double* __restrict__ spt,
    const float* __restrict__ C, int NF,
    const int* __restrict__ ncls, float* __restrict__ out) {
  const int lane = threadIdx.x;
  const int nc = ncls[0];
  double spf = spt[lane] * exp(-((double)(64 - lane)) * log(64.0));
  for (int off = 32; off; off >>= 1) spf += __shfl_down(spf, off);

  double hl1 = 0.0, hl2 = 0.0;
  const double beta = 1.0 / (double)nc + 1e-13;
  for (int cc = 0; cc < nc; ++cc) {
    bool ip = (lane % nc) == cc;
    double ps = 0.0, ns = 0.0;
    for (int j = 0; j < 64; ++j) {
      double dv = (double)Dm[lane * 64 + j];
      bool jp = (j % nc) == cc;
      if (ip && jp) ps += dv;
      if (!ip && !jp) ns += dv;
    }
    for (int off = 32; off; off >>= 1) {
      ps += __shfl_down(ps, off);
      ns += __shfl_down(ns, off);
    }
    int npos = 0;
    for (int q = 0; q < 64; ++q) if (q % nc == cc) npos++;
    int nneg = 64 - npos;
    hl2 += ps / ((double)npos * (double)npos);
    hl1 += -(ns / ((double)nneg * (double)nneg)) / beta;
  }
  if (lane == 0) {
    double l1 = 0.0, l2 = 0.0;
    for (int q = 0; q < NF; ++q) { double cv = (double)C[q]; l1 += fabs(cv); l2 += cv * cv; }
    l2 = sqrt(l2); if (l2 < 1e-12) l2 = 1e-12;
    double dims = sqrt((double)NF);
    double sc = (dims - l1 / l2) / (dims - 1.0);
    out[0] = (float)(sc + hl2 + hl1 + spf);
  }
}

// ---------------------------------------------------------------------------
extern "C" void kernel_launch(void* const* d_in, const int* in_sizes, int n_in,
                              void* d_out, int out_size, void* d_ws, size_t ws_size,
                              hipStream_t stream) {
  (void)n_in; (void)out_size; (void)ws_size;
  const float* x    = (const float*)d_in[0];
  const float* rs   = (const float*)d_in[1];
  const float* C    = (const float*)d_in[2];
  const int*   esrc = (const int*)d_in[3];
  const int*   edst = (const int*)d_in[4];
  const int*   ncls = (const int*)d_in[5];
  float* out = (float*)d_out;

  const int F0   = in_sizes[0] / (64 * 128);
  const int R    = in_sizes[1] / (64 * 128);
  const int NF   = in_sizes[2];
  const int E    = in_sizes[3] / 64;
  const int DTOT = F0 + R;
  const int NCH  = (DTOT + 127) / 128;
  const float rscale = (float)(1.0 / sqrt((double)R));

  char* ws = (char*)d_ws;
  size_t off = 0;
  float*  L    = (float*)(ws + off);  off += (size_t)64 * NN * NN * 4;
  float*  W    = (float*)(ws + off);  off += (size_t)64 * NN * NN * 4;
  float*  G    = (float*)(ws + off);  off += (size_t)64 * NN * NN * 4;
  double* L2d  = (double*)(ws + off); off += (size_t)64 * NN * NN * 8;
  double* L3d  = (double*)(ws + off); off += (size_t)64 * NN * NN * 8;
  double* L4d  = (double*)(ws + off); off += (size_t)64 * NN * NN * 8;
  float*  emb  = (float*)(ws + off);  off += (size_t)64 * 1152 * 4;
  double* spt  = (double*)(ws + off); off += (size_t)64 * 8;
  float*  Dm   = (float*)(ws + off);  off += (size_t)64 * 64 * 4;

  // W and G are contiguous: one memset covers both
  hipMemsetAsync(W, 0, (size_t)2 * 64 * NN * NN * 4, stream);

  const int lds1 = (NN * SM + NN) * 4;             // 66560
  const int ldsp = NN * SD * 8;                    // 133120 (f64 staging)
  const int lds2 = 16 * RS * 8 + 8 * 16 * SS * 8 + 16 * SS * 8;  // 36480
  const int lds3 = NN * TS * 4 * 2;                // 135168
  hipFuncSetAttribute((const void*)k1_lap_pow2, hipFuncAttributeMaxDynamicSharedMemorySize, lds1);
  hipFuncSetAttribute((const void*)k1_pow34,    hipFuncAttributeMaxDynamicSharedMemorySize, ldsp);
  hipFuncSetAttribute((const void*)k2_filter,   hipFuncAttributeMaxDynamicSharedMemorySize, lds2);
  hipFuncSetAttribute((const void*)k3_fused,    hipFuncAttributeMaxDynamicSharedMemorySize, lds3);

  k1_lap_pow2<<<64, 512, lds1, stream>>>(esrc, edst, E, L, L2d);
  k1_pow34<<<128, 512, ldsp, stream>>>(L, L2d, L3d, L4d);
  k2_filter<<<64 * NF, 512, lds2, stream>>>(L, L2d, L3d, L4d, C, NF, W);
  k3_fused<<<64 * NCH, 512, lds3, stream>>>(x, rs, W, G, emb, F0, R, DTOT, NCH, rscale);
  k45_fused<<<128, 256, 0, stream>>>(G, spt, emb, Dm, DTOT);
  k5b_final<<<1, 64, 0, stream>>>(Dm, spt, C, NF, ncls, out);
}

// Round 17
// 638.484 us; speedup vs baseline: 1.0378x; 1.0042x over previous
//
#include <hip/hip_runtime.h>
#include <math.h>

#define NN 128
#define SM 129   // padded LDS stride for 128-wide f32 tiles
#define TS 132   // k3 tile stride (16B-aligned rows -> float4 LDS loads)
#define RS 132   // row-panel stride (doubles)
#define SS 17    // per-wave scratch stride (doubles)
#define SD 130   // padded LDS stride (doubles) for f64 matrix staging
#define EP 132   // emb-partial stride (floats)

typedef double d4 __attribute__((ext_vector_type(4)));

// ---------------------------------------------------------------------------
// K1 (R17): build symmetric-normalized Laplacian per graph (f32) only.
// ---------------------------------------------------------------------------
__global__ __launch_bounds__(256) void k1_lap(
    const int* __restrict__ src, const int* __restrict__ dst,
    int E, float* __restrict__ Lout) {
  extern __shared__ float sm1[];            // A[128*129] + dinv[128]
  float* A    = sm1;
  float* dinv = sm1 + NN * SM;
  const int g   = blockIdx.x;
  const int tid = threadIdx.x;

  for (int e = tid; e < NN * NN; e += 256) {
    int i = e >> 7, j = e & 127;
    A[i * SM + j] = 0.f;
  }
  __syncthreads();
  const int* s = src + (size_t)g * E;
  const int* d = dst + (size_t)g * E;
  for (int e = tid; e < E; e += 256) {
    int a = s[e], b = d[e];
    A[a * SM + b] = 1.f;     // benign races: all write 1.0
    A[b * SM + a] = 1.f;
  }
  __syncthreads();
  if (tid < NN) {
    float acc = 0.f;
    for (int j = 0; j < NN; ++j) acc += A[tid * SM + j];
    dinv[tid] = (acc > 0.f) ? (float)(1.0 / sqrt((double)acc)) : 0.f;
  }
  __syncthreads();
  float* Lg = Lout + (size_t)g * NN * NN;
  for (int e = tid; e < NN * NN; e += 256) {
    int i = e >> 7, j = e & 127;
    Lg[e] = ((i == j) ? 1.f : 0.f) - dinv[i] * dinv[j] * A[i * SM + j];
  }
}

// ---------------------------------------------------------------------------
// KPOW2 (R17): L2 = L @ L, 256 blocks (g = bid>>2, quarter q = bid&3 =
// 32-row band). B = L staged f64 in LDS; wave w: 16-row band q*32+16*(w&1),
// cb pair 2*(w>>1). Full-machine version of the old half-idle kernel.
// ---------------------------------------------------------------------------
__global__ __launch_bounds__(512, 1) void kpow2(
    const float* __restrict__ L, double* __restrict__ L2) {
  extern __shared__ double Bs[];            // 128 x 130 f64
  const int bid = blockIdx.x;
  const int g = bid >> 2, q = bid & 3;
  const int tid = threadIdx.x;
  const int wv = tid >> 6, ln = tid & 63;
  const int m  = ln & 15, kq = ln >> 4;
  const int rb = 32 * q + 16 * (wv & 1);    // row-band base
  const int cb0 = 2 * (wv >> 1);            // 2 col tiles

  int rIdx[4], cIdx[4];
  {
    d4 z = {0.0, 0.0, 0.0, 0.0};
    d4 pr = __builtin_amdgcn_mfma_f64_16x16x4f64((double)m, 1.0, z, 0, 0, 0);
    d4 pc = __builtin_amdgcn_mfma_f64_16x16x4f64(1.0, (double)m, z, 0, 0, 0);
#pragma unroll
    for (int r = 0; r < 4; ++r) {
      rIdx[r] = ((int)(pr[r] * 0.25 + 0.5)) & 15;
      cIdx[r] = ((int)(pc[r] * 0.25 + 0.5)) & 15;
    }
  }

  const float* Lg = L + (size_t)g * NN * NN;
  for (int e = tid; e < NN * NN; e += 512) {
    int i = e >> 7, j = e & 127;
    Bs[i * SD + j] = (double)Lg[e];
  }
  __syncthreads();

  d4 acc[2];
#pragma unroll
  for (int c = 0; c < 2; ++c) {
    acc[c][0] = 0.0; acc[c][1] = 0.0; acc[c][2] = 0.0; acc[c][3] = 0.0;
  }
  for (int kc = 0; kc < 32; ++kc) {
    double a = Bs[(rb + m) * SD + 4 * kc + kq];
#pragma unroll
    for (int c = 0; c < 2; ++c) {
      double b = Bs[(4 * kc + kq) * SD + 16 * (cb0 + c) + m];
      acc[c] = __builtin_amdgcn_mfma_f64_16x16x4f64(a, b, acc[c], 0, 0, 0);
    }
  }
  double* out = L2 + (size_t)g * NN * NN;
#pragma unroll
  for (int c = 0; c < 2; ++c)
#pragma unroll
    for (int r = 0; r < 4; ++r)
      out[(rb + rIdx[r]) * NN + 16 * (cb0 + c) + cIdx[r]] = acc[c][r];
}

// ---------------------------------------------------------------------------
// KPOW34 (R17): 256 blocks = g(6b) x half(1b) x job(1b).
// job 0: L3 = L2 @ L ; job 1: L4 = L2 @ L2. Each block: 64-row half-band.
// Wave w: band 64h + 16*(w&3), cb quad 4*(w>>2). B staged f64 in LDS;
// A rows read from global L2 (L2/L3-cached).
// ---------------------------------------------------------------------------
__global__ __launch_bounds__(512, 1) void kpow34(
    const float* __restrict__ L, const double* __restrict__ L2,
    double* __restrict__ L3, double* __restrict__ L4) {
  extern __shared__ double Bs[];            // 128 x 130 f64
  const int bid = blockIdx.x;
  const int g = bid >> 2, h = (bid >> 1) & 1, job = bid & 1;
  const int tid = threadIdx.x;
  const int wv = tid >> 6, ln = tid & 63;
  const int m  = ln & 15, kq = ln >> 4;
  const int rb = 64 * h + 16 * (wv & 3);
  const int cb0 = 4 * (wv >> 2);

  int rIdx[4], cIdx[4];
  {
    d4 z = {0.0, 0.0, 0.0, 0.0};
    d4 pr = __builtin_amdgcn_mfma_f64_16x16x4f64((double)m, 1.0, z, 0, 0, 0);
    d4 pc = __builtin_amdgcn_mfma_f64_16x16x4f64(1.0, (double)m, z, 0, 0, 0);
#pragma unroll
    for (int r = 0; r < 4; ++r) {
      rIdx[r] = ((int)(pr[r] * 0.25 + 0.5)) & 15;
      cIdx[r] = ((int)(pc[r] * 0.25 + 0.5)) & 15;
    }
  }

  const float*  Lg  = L  + (size_t)g * NN * NN;
  const double* L2g = L2 + (size_t)g * NN * NN;
  if (job == 0) {
    for (int e = tid; e < NN * NN; e += 512) {
      int i = e >> 7, j = e & 127;
      Bs[i * SD + j] = (double)Lg[e];
    }
  } else {
    for (int e = tid; e < NN * NN; e += 512) {
      int i = e >> 7, j = e & 127;
      Bs[i * SD + j] = L2g[e];
    }
  }
  __syncthreads();

  d4 acc[4];
#pragma unroll
  for (int c = 0; c < 4; ++c) {
    acc[c][0] = 0.0; acc[c][1] = 0.0; acc[c][2] = 0.0; acc[c][3] = 0.0;
  }
  for (int kc = 0; kc < 32; ++kc) {
    double a = L2g[(rb + m) * NN + 4 * kc + kq];
#pragma unroll
    for (int c = 0; c < 4; ++c) {
      double b = Bs[(4 * kc + kq) * SD + 16 * (cb0 + c) + m];
      acc[c] = __builtin_amdgcn_mfma_f64_16x16x4f64(a, b, acc[c], 0, 0, 0);
    }
  }
  double* out = (job == 0 ? L3 : L4) + (size_t)g * NN * NN;
#pragma unroll
  for (int c = 0; c < 4; ++c)
#pragma unroll
    for (int r = 0; r < 4; ++r)
      out[(rb + rIdx[r]) * NN + 16 * (cb0 + c) + cIdx[r]] = acc[c][r];
}

// ---------------------------------------------------------------------------
// K2 (R14, unchanged): algebraic assembly + blocked GJ with serial-Pi.
// 268us stable; MFMA-busy ~73us (GJ floor), VALU 13%, rest barrier stall.
// ---------------------------------------------------------------------------
__global__ __launch_bounds__(512, 4) void k2_filter(
    const float* __restrict__ L, const double* __restrict__ L2,
    const double* __restrict__ L3, const double* __restrict__ L4,
    const float* __restrict__ C, int NF, float* __restrict__ W) {
  extern __shared__ char smraw[];
  double* Rp  = (double*)smraw;                      // row panel 16x132
  double* Scd = (double*)(smraw + 16 * RS * 8);      // 8 wave scratches 16x17
  double* Pv  = (double*)(smraw + 16 * RS * 8 + 8 * 16 * SS * 8); // Pi 16x17

  const int bid = blockIdx.x;
  const int g = bid / NF, f = bid % NF;
  const int tid = threadIdx.x;
  const int wv = tid >> 6, ln = tid & 63;
  const int m  = ln & 15, kq = ln >> 4;
  double* S = Scd + wv * 16 * SS;

  double csum = 0.0;
  for (int q = 0; q < NF; ++q) { double c = (double)C[q]; csum += c * c; }
  double cn = sqrt(csum); if (cn < 1e-12) cn = 1e-12;
  const double a4 = 6.25e-6;                         // (STEP/2)^4
  const double coef = 1.4142135623730951 * a4 * ((double)C[f] / cn);
  const float  bf = (float)((double)f * 0.1);
  const double bb = (double)bf;
  const double c3 = -4.0 * bb;
  const double c2 = 6.0 * bb * bb;
  const double c1 = -4.0 * bb * bb * bb;
  const double c0 = bb * bb * bb * bb + a4;

  int rIdx[4], cIdx[4];
  {
    d4 z = {0.0, 0.0, 0.0, 0.0};
    d4 pr = __builtin_amdgcn_mfma_f64_16x16x4f64((double)m, 1.0, z, 0, 0, 0);
    d4 pc = __builtin_amdgcn_mfma_f64_16x16x4f64(1.0, (double)m, z, 0, 0, 0);
#pragma unroll
    for (int r = 0; r < 4; ++r) {
      rIdx[r] = ((int)(pr[r] * 0.25 + 0.5)) & 15;
      cIdx[r] = ((int)(pc[r] * 0.25 + 0.5)) & 15;
    }
  }

  // phase A: assemble T (D-layout) from the power matrices -- pure n^2
  const float*  Lg  = L  + (size_t)g * NN * NN;
  const double* L2g = L2 + (size_t)g * NN * NN;
  const double* L3g = L3 + (size_t)g * NN * NN;
  const double* L4g = L4 + (size_t)g * NN * NN;
  d4 T[8];
#pragma unroll
  for (int cb = 0; cb < 8; ++cb)
#pragma unroll
    for (int r = 0; r < 4; ++r) {
      int i = 16 * wv + rIdx[r], j = 16 * cb + cIdx[r];
      int idx = i * NN + j;
      double v = L4g[idx];
      v = fma(c3, L3g[idx], v);
      v = fma(c2, L2g[idx], v);
      v = fma(c1, (double)Lg[idx], v);
      if (i == j) v += c0;
      T[cb][r] = v;
    }

  // phase 4: blocked GJ, 8 steps, 3 block-barriers each, NOT unrolled
#pragma unroll 1
  for (int t = 0; t < 8; ++t) {
    if (wv == t) {
#pragma unroll
      for (int cb = 0; cb < 8; ++cb)
#pragma unroll
        for (int r = 0; r < 4; ++r)
          Rp[rIdx[r] * RS + 16 * cb + cIdx[r]] = T[cb][r];
    }
    __syncthreads();                                 // B1 (Rp visible)

    if (wv == t) {
      double sr[4];
#pragma unroll
      for (int r = 0; r < 4; ++r) sr[r] = Rp[(4 * r + kq) * RS + 16 * t + m];
#pragma unroll
      for (int k = 0; k < 16; ++k) {
        const int kr = k >> 2, kl = k & 3;
        double pv   = __shfl(sr[kr], 16 * kl + k);
        double rowv = __shfl(sr[kr], 16 * kl + m);
        double cv[4];
#pragma unroll
        for (int r = 0; r < 4; ++r) cv[r] = __shfl(sr[r], 16 * kq + k);
        double dp = 1.0 / pv;
#pragma unroll
        for (int r = 0; r < 4; ++r) {
          int i = 4 * r + kq;
          double nv;
          if (i == k)      nv = (m == k) ? dp : rowv * dp;
          else if (m == k) nv = -cv[r] * dp;
          else             nv = fma(-(cv[r] * dp), rowv, sr[r]);
          sr[r] = nv;
        }
      }
#pragma unroll
      for (int r = 0; r < 4; ++r) Pv[(4 * r + kq) * SS + m] = sr[r];
    }
    __syncthreads();                                 // B2 (Pi visible)

#pragma unroll
    for (int cb = 0; cb < 8; ++cb) {
      if (cb != t) continue;
      if (wv == t) {
#pragma unroll
        for (int r = 0; r < 4; ++r) T[cb][r] = Pv[rIdx[r] * SS + cIdx[r]];
      } else {
#pragma unroll
        for (int r = 0; r < 4; ++r) S[rIdx[r] * SS + cIdx[r]] = T[cb][r];
        __builtin_amdgcn_wave_barrier();
        d4 ncv = {0.0, 0.0, 0.0, 0.0};
#pragma unroll
        for (int kc = 0; kc < 4; ++kc) {
          double a = S[m * SS + 4 * kc + kq];
          double b = -Pv[(4 * kc + kq) * SS + m];
          ncv = __builtin_amdgcn_mfma_f64_16x16x4f64(a, b, ncv, 0, 0, 0);
        }
        T[cb] = ncv;
        __builtin_amdgcn_wave_barrier();
#pragma unroll
        for (int r = 0; r < 4; ++r) S[rIdx[r] * SS + cIdx[r]] = T[cb][r];
      }
    }
    __builtin_amdgcn_wave_barrier();

    const double* asrc = (wv == t) ? Pv : S;
#pragma unroll
    for (int cb = 0; cb < 8; ++cb) {
      if (cb == t) continue;
      d4 acc;
      if (wv == t) { acc[0] = 0.0; acc[1] = 0.0; acc[2] = 0.0; acc[3] = 0.0; }
      else         { acc = T[cb]; }
#pragma unroll
      for (int kc = 0; kc < 4; ++kc) {
        double a = asrc[m * SS + 4 * kc + kq];
        double b = Rp[(4 * kc + kq) * RS + 16 * cb + m];
        acc = __builtin_amdgcn_mfma_f64_16x16x4f64(a, b, acc, 0, 0, 0);
      }
      T[cb] = acc;
    }
    __syncthreads();                                 // B3 (Rp/Pv reads done)
  }

  // phase 5: W += coef * K^{-1}
  float* Wg = W + (size_t)g * NN * NN;
#pragma unroll
  for (int cb = 0; cb < 8; ++cb)
#pragma unroll
    for (int r = 0; r < 4; ++r)
      atomicAdd(&Wg[(16 * wv + rIdx[r]) * NN + 16 * cb + cIdx[r]],
                (float)(coef * T[cb][r]));
}

// ---------------------------------------------------------------------------
// K3 (R16, unchanged): fp32 VALU fused kernel, stride-132 float4 LDS loads.
// ---------------------------------------------------------------------------
__global__ __launch_bounds__(512, 1) void k3_fused(
    const float* __restrict__ x, const float* __restrict__ rs,
    const float* __restrict__ W, float* __restrict__ G,
    float* __restrict__ emb, int F0, int R, int DTOT, int NCH,
    float rscale) {
  extern __shared__ float sm3[];
  float* ldsW = sm3;                 // 128*132, later yT
  float* ldsX = sm3 + NN * TS;       // 128*132, later emb partials (32x132)
  const int bid = blockIdx.x;
  const int g = bid / NCH;
  const int c = bid % NCH;
  const int d0 = c * 128;
  const int tid = threadIdx.x, tr = tid >> 4, tc = tid & 15;

  const float* Wg = W + (size_t)g * NN * NN;
  for (int e = tid; e < NN * NN; e += 512) {
    int k = e >> 7, i = e & 127;
    ldsW[k * TS + i] = Wg[e];
  }
  const float* xg = x + (size_t)g * NN * F0;
  const float* rg = rs + (size_t)g * NN * R;
  for (int e = tid; e < NN * NN; e += 512) {
    int k = e >> 7, dl = e & 127;
    int d = d0 + dl;
    float v = 0.f;
    if (d < DTOT) v = (d < F0) ? xg[k * F0 + d] : rg[k * R + (d - F0)] * rscale;
    ldsX[k * TS + dl] = v;
  }
  __syncthreads();

  float acc[4][8];
#pragma unroll
  for (int v = 0; v < 4; ++v)
#pragma unroll
    for (int u = 0; u < 8; ++u) acc[v][u] = 0.f;
  for (int k = 0; k < NN; ++k) {
    float4 w4 = *(const float4*)(ldsW + k * TS + 4 * tr);   // W symmetric rows
    float xv[8];
#pragma unroll
    for (int u = 0; u < 8; ++u) xv[u] = ldsX[k * TS + tc + 16 * u];
    float wvv[4] = {w4.x, w4.y, w4.z, w4.w};
#pragma unroll
    for (int v = 0; v < 4; ++v)
#pragma unroll
      for (int u = 0; u < 8; ++u) acc[v][u] = fmaf(wvv[v], xv[u], acc[v][u]);
  }
#pragma unroll
  for (int v = 0; v < 4; ++v)
#pragma unroll
    for (int u = 0; u < 8; ++u)
      acc[v][u] = ldsX[(4 * tr + v) * TS + tc + 16 * u] - acc[v][u];
  __syncthreads();

#pragma unroll
  for (int v = 0; v < 4; ++v)
#pragma unroll
    for (int u = 0; u < 8; ++u)
      ldsW[(tc + 16 * u) * TS + 4 * tr + v] = acc[v][u];
#pragma unroll
  for (int u = 0; u < 8; ++u) {
    float s = 0.f;
#pragma unroll
    for (int v = 0; v < 4; ++v) s += acc[v][u];
    ldsX[tr * EP + tc + 16 * u] = s;
  }
  __syncthreads();

  float gg[4][8];
#pragma unroll
  for (int v = 0; v < 4; ++v)
#pragma unroll
    for (int u = 0; u < 8; ++u) gg[v][u] = 0.f;
  for (int dl = 0; dl < NN; ++dl) {
    float4 a4v = *(const float4*)(ldsW + dl * TS + 4 * tr);
    float bv[8];
#pragma unroll
    for (int u = 0; u < 8; ++u) bv[u] = ldsW[dl * TS + tc + 16 * u];
    float av[4] = {a4v.x, a4v.y, a4v.z, a4v.w};
#pragma unroll
    for (int v = 0; v < 4; ++v)
#pragma unroll
      for (int u = 0; u < 8; ++u) gg[v][u] = fmaf(av[v], bv[u], gg[v][u]);
  }
  float* Gg = G + (size_t)g * NN * NN;
#pragma unroll
  for (int v = 0; v < 4; ++v)
#pragma unroll
    for (int u = 0; u < 8; ++u)
      atomicAdd(&Gg[(4 * tr + v) * NN + tc + 16 * u], gg[v][u]);

  if (tid < 128) {
    int d = d0 + tid;
    if (d < DTOT) {
      float s = 0.f;
      for (int tt = 0; tt < 32; ++tt) s += ldsX[tt * EP + tid];
      emb[(size_t)g * 1152 + d] = s * (1.f / 128.f);
    }
  }
}

// ---------------------------------------------------------------------------
// K45 (fused): blocks 0..63 = k4 (sp terms from G); 64..127 = k5a (cdist)
// ---------------------------------------------------------------------------
__global__ __launch_bounds__(256) void k45_fused(
    const float* __restrict__ G, double* __restrict__ spt,
    const float* __restrict__ emb, float* __restrict__ Dm, int DTOT) {
  __shared__ float inr[NN];
  __shared__ double red[4];
  const int bid = blockIdx.x, tid = threadIdx.x;
  if (bid < 64) {
    const int g = bid;
    const float* Gg = G + (size_t)g * NN * NN;
    if (tid < NN) {
      float n = sqrtf(fmaxf(Gg[tid * NN + tid], 0.f));
      inr[tid] = 1.f / fmaxf(n, 1e-12f);
    }
    __syncthreads();
    double s = 0.0;
    for (int e = tid; e < NN * NN; e += 256) {
      int i = e >> 7, j = e & 127;
      s += (double)(fabsf(Gg[e]) * inr[i] * inr[j]);
    }
    for (int off = 32; off; off >>= 1) s += __shfl_down(s, off);
    int wave = tid >> 6, lane = tid & 63;
    if (lane == 0) red[wave] = s;
    __syncthreads();
    if (tid == 0) spt[g] = -(red[0] + red[1] + red[2] + red[3]) / (double)(NN * NN);
  } else {
    const int i = bid - 64;
    const int wv = tid >> 6, l = tid & 63;
    float ei[18];
#pragma unroll
    for (int s = 0; s < 18; ++s) {
      int d = l + 64 * s;
      ei[s] = (d < DTOT) ? emb[(size_t)i * 1152 + d] : 0.f;
    }
    for (int jj = 0; jj < 16; ++jj) {
      int j = 4 * jj + wv;
      float acc = 0.f;
#pragma unroll
      for (int s = 0; s < 18; ++s) {
        int d = l + 64 * s;
        if (d < DTOT) {
          float df = ei[s] - emb[(size_t)j * 1152 + d];
          acc = fmaf(df, df, acc);
        }
      }
      for (int off = 32; off; off >>= 1) acc += __shfl_down(acc, off);
      if (l == 0) Dm[i * 64 + j] = (acc > 0.f) ? sqrtf(acc) : 0.f;
    }
  }
}

// ---------------------------------------------------------------------------
// K5b: final scalar (single wave)
// ---------------------------------------------------------------------------
__global__ __launch_bounds__(64) void k5b_final(
    const float* __restrict__ Dm, const double* __restrict__ spt,
    const float* __restrict__ C, int NF,
    const int* __restrict__ ncls, float* __restrict__ out) {
  const int lane = threadIdx.x;
  const int nc = ncls[0];
  double spf = spt[lane] * exp(-((double)(64 - lane)) * log(64.0));
  for (int off = 32; off; off >>= 1) spf += __shfl_down(spf, off);

  double hl1 = 0.0, hl2 = 0.0;
  const double beta = 1.0 / (double)nc + 1e-13;
  for (int cc = 0; cc < nc; ++cc) {
    bool ip = (lane % nc) == cc;
    double ps = 0.0, ns = 0.0;
    for (int j = 0; j < 64; ++j) {
      double dv = (double)Dm[lane * 64 + j];
      bool jp = (j % nc) == cc;
      if (ip && jp) ps += dv;
      if (!ip && !jp) ns += dv;
    }
    for (int off = 32; off; off >>= 1) {
      ps += __shfl_down(ps, off);
      ns += __shfl_down(ns, off);
    }
    int npos = 0;
    for (int q = 0; q < 64; ++q) if (q % nc == cc) npos++;
    int nneg = 64 - npos;
    hl2 += ps / ((double)npos * (double)npos);
    hl1 += -(ns / ((double)nneg * (double)nneg)) / beta;
  }
  if (lane == 0) {
    double l1 = 0.0, l2 = 0.0;
    for (int q = 0; q < NF; ++q) { double cv = (double)C[q]; l1 += fabs(cv); l2 += cv * cv; }
    l2 = sqrt(l2); if (l2 < 1e-12) l2 = 1e-12;
    double dims = sqrt((double)NF);
    double sc = (dims - l1 / l2) / (dims - 1.0);
    out[0] = (float)(sc + hl2 + hl1 + spf);
  }
}

// ---------------------------------------------------------------------------
extern "C" void kernel_launch(void* const* d_in, const int* in_sizes, int n_in,
                              void* d_out, int out_size, void* d_ws, size_t ws_size,
                              hipStream_t stream) {
  (void)n_in; (void)out_size; (void)ws_size;
  const float* x    = (const float*)d_in[0];
  const float* rs   = (const float*)d_in[1];
  const float* C    = (const float*)d_in[2];
  const int*   esrc = (const int*)d_in[3];
  const int*   edst = (const int*)d_in[4];
  const int*   ncls = (const int*)d_in[5];
  float* out = (float*)d_out;

  const int F0   = in_sizes[0] / (64 * 128);
  const int R    = in_sizes[1] / (64 * 128);
  const int NF   = in_sizes[2];
  const int E    = in_sizes[3] / 64;
  const int DTOT = F0 + R;
  const int NCH  = (DTOT + 127) / 128;
  const float rscale = (float)(1.0 / sqrt((double)R));

  char* ws = (char*)d_ws;
  size_t off = 0;
  float*  L    = (float*)(ws + off);  off += (size_t)64 * NN * NN * 4;
  float*  W    = (float*)(ws + off);  off += (size_t)64 * NN * NN * 4;
  float*  G    = (float*)(ws + off);  off += (size_t)64 * NN * NN * 4;
  double* L2d  = (double*)(ws + off); off += (size_t)64 * NN * NN * 8;
  double* L3d  = (double*)(ws + off); off += (size_t)64 * NN * NN * 8;
  double* L4d  = (double*)(ws + off); off += (size_t)64 * NN * NN * 8;
  float*  emb  = (float*)(ws + off);  off += (size_t)64 * 1152 * 4;
  double* spt  = (double*)(ws + off); off += (size_t)64 * 8;
  float*  Dm   = (float*)(ws + off);  off += (size_t)64 * 64 * 4;

  // W and G are contiguous: one memset covers both
  hipMemsetAsync(W, 0, (size_t)2 * 64 * NN * NN * 4, stream);

  const int lds1 = (NN * SM + NN) * 4;             // 66560
  const int ldsp = NN * SD * 8;                    // 133120 (f64 staging)
  const int lds2 = 16 * RS * 8 + 8 * 16 * SS * 8 + 16 * SS * 8;  // 36480
  const int lds3 = NN * TS * 4 * 2;                // 135168
  hipFuncSetAttribute((const void*)k1_lap,    hipFuncAttributeMaxDynamicSharedMemorySize, lds1);
  hipFuncSetAttribute((const void*)kpow2,     hipFuncAttributeMaxDynamicSharedMemorySize, ldsp);
  hipFuncSetAttribute((const void*)kpow34,    hipFuncAttributeMaxDynamicSharedMemorySize, ldsp);
  hipFuncSetAttribute((const void*)k2_filter, hipFuncAttributeMaxDynamicSharedMemorySize, lds2);
  hipFuncSetAttribute((const void*)k3_fused,  hipFuncAttributeMaxDynamicSharedMemorySize, lds3);

  k1_lap<<<64, 256, lds1, stream>>>(esrc, edst, E, L);
  kpow2<<<256, 512, ldsp, stream>>>(L, L2d);
  kpow34<<<256, 512, ldsp, stream>>>(L, L2d, L3d, L4d);
  k2_filter<<<64 * NF, 512, lds2, stream>>>(L, L2d, L3d, L4d, C, NF, W);
  k3_fused<<<64 * NCH, 512, lds3, stream>>>(x, rs, W, G, emb, F0, R, DTOT, NCH, rscale);
  k45_fused<<<128, 256, 0, stream>>>(G, spt, emb, Dm, DTOT);
  k5b_final<<<1, 64, 0, stream>>>(Dm, spt, C, NF, ncls, out);
}